// Round 4
// baseline (290.589 us; speedup 1.0000x reference)
//
#include <hip/hip_runtime.h>

// BusStopGNN round 4:
//  - mm64 rewritten as tiled GEMM (64 rows/block, 4x4 register tile/thread,
//    X staged in padded LDS) -- round-3 version spilled (acc[64]+xr[64] vs
//    VGPR_Count=68) and ran at 6.7% VALUBusy with a 391-block grid.
//  - linear head fused into layer-2 gather (wave shfl reduction), k_out gone.
//  - gather unrolled 8-deep for more memory-level parallelism.
// CSR build via two-level counting sort unchanged (no global atomics).

#define GNN_N 100000
#define GNN_E 1600000
#define NBUCK 391   // ceil(N/256), bucket = dst >> 8
#define NBLK  256
#define EPB   6250  // E / NBLK

// ---- Pass 1: per-block LDS histogram over dst buckets ----
__global__ __launch_bounds__(256) void k_hist(const int* __restrict__ dst,
                                              int* __restrict__ hist) {
    __shared__ int h[NBUCK];
    for (int i = threadIdx.x; i < NBUCK; i += 256) h[i] = 0;
    __syncthreads();
    int b = blockIdx.x;
    int e0 = b * EPB, e1 = min(e0 + EPB, GNN_E);
    for (int e = e0 + threadIdx.x; e < e1; e += 256)
        atomicAdd(&h[dst[e] >> 8], 1);
    __syncthreads();
    for (int i = threadIdx.x; i < NBUCK; i += 256)
        hist[b * NBUCK + i] = h[i];
}

// ---- Pass 2: column scan + bucket bases ----
__global__ __launch_bounds__(512) void k_colscan(int* __restrict__ hist,
                                                 int* __restrict__ bbase) {
    __shared__ int tot[NBUCK];
    int k = threadIdx.x;
    if (k < NBUCK) {
        int run = 0;
        for (int b = 0; b < NBLK; ++b) {
            int idx = b * NBUCK + k;
            int t = hist[idx];
            hist[idx] = run;
            run += t;
        }
        tot[k] = run;
    }
    __syncthreads();
    if (threadIdx.x == 0) {
        int run = 0;
        for (int i = 0; i < NBUCK; ++i) { int t = tot[i]; tot[i] = run; run += t; }
    }
    __syncthreads();
    if (k < NBUCK) bbase[k] = tot[k];
    if (threadIdx.x == 0) bbase[NBUCK] = GNN_E;
}

// ---- Pass 3: partition edges into bucket regions; pack (dst&255)<<17 | src ----
__global__ __launch_bounds__(256) void k_part(const int* __restrict__ src,
                                              const int* __restrict__ dst,
                                              const int* __restrict__ hist,
                                              const int* __restrict__ bbase,
                                              unsigned int* __restrict__ part) {
    __shared__ int off[NBUCK];
    int b = blockIdx.x;
    for (int i = threadIdx.x; i < NBUCK; i += 256)
        off[i] = bbase[i] + hist[b * NBUCK + i];
    __syncthreads();
    int e0 = b * EPB, e1 = min(e0 + EPB, GNN_E);
    for (int e = e0 + threadIdx.x; e < e1; e += 256) {
        int d = dst[e], s = src[e];
        int slot = atomicAdd(&off[d >> 8], 1);
        part[slot] = ((unsigned int)(d & 255) << 17) | (unsigned int)s;
    }
}

// ---- Pass 4: per-bucket counting sort -> csr, rowptr, deg, dis ----
__global__ __launch_bounds__(256) void k_bsort(const unsigned int* __restrict__ part,
                                               const int* __restrict__ bbase,
                                               int* __restrict__ csr,
                                               int* __restrict__ rowptr,
                                               int* __restrict__ deg,
                                               float* __restrict__ dis) {
    __shared__ int cnt[256];
    __shared__ int pos[256];
    int k = blockIdx.x;
    int t = threadIdx.x;
    cnt[t] = 0;
    __syncthreads();
    int e0 = bbase[k], e1 = bbase[k + 1];
    for (int e = e0 + t; e < e1; e += 256)
        atomicAdd(&cnt[part[e] >> 17], 1);
    __syncthreads();
    if (t == 0) {
        int run = 0;
        for (int i = 0; i < 256; ++i) { int c = cnt[i]; pos[i] = run; run += c; }
    }
    __syncthreads();
    int node = k * 256 + t;
    if (node < GNN_N) {
        rowptr[node] = e0 + pos[t];
        deg[node]    = cnt[t];
        dis[node]    = rsqrtf((float)cnt[t] + 1.0f);
    }
    __syncthreads();
    for (int e = e0 + t; e < e1; e += 256) {
        unsigned int p = part[e];
        int slot = e0 + atomicAdd(&pos[p >> 17], 1);
        csr[slot] = (int)(p & 0x1FFFF);
    }
}

// ---- tiled 64x64 matmul, dis-scale epilogue: Y[row] = (X@W)[row]*dis[row] ----
// 64 rows/block (grid ~1563), thread (ti,tj) computes rows ti*4..+3, cols tj*4..+3.
// 16 acc VGPRs/thread -> no spills; X in padded LDS (stride 68 floats).
__global__ __launch_bounds__(256) void k_mm64(const float* __restrict__ X,
                                              const float* __restrict__ W,
                                              const float* __restrict__ dis,
                                              float* __restrict__ Y, int n) {
    __shared__ float  Xs[64][68];     // pad to 68 floats: 16B-aligned rows, bank-spread
    __shared__ float4 Ws[64 * 16];    // W[k][j4]
    int tid = threadIdx.x;
    int base = blockIdx.x * 64;
    for (int i = tid; i < 1024; i += 256)
        Ws[i] = ((const float4*)W)[i];
#pragma unroll
    for (int i = 0; i < 4; ++i) {     // 1024 float4s of X: 4 per thread
        int g = i * 256 + tid;
        int r = g >> 4, c4 = g & 15;
        int row = base + r;
        float4 v = (row < n) ? ((const float4*)(X + (size_t)row * 64))[c4]
                             : make_float4(0.f, 0.f, 0.f, 0.f);
        *(float4*)&Xs[r][c4 * 4] = v;
    }
    __syncthreads();
    int tj = tid & 15;                // column float4
    int ti = tid >> 4;                // row group: rows ti*4 .. ti*4+3
    float4 a0 = {0,0,0,0}, a1 = {0,0,0,0}, a2 = {0,0,0,0}, a3 = {0,0,0,0};
#pragma unroll
    for (int k4 = 0; k4 < 16; ++k4) { // k-quad
        float4 x0 = *(const float4*)&Xs[ti * 4 + 0][k4 * 4];
        float4 x1 = *(const float4*)&Xs[ti * 4 + 1][k4 * 4];
        float4 x2 = *(const float4*)&Xs[ti * 4 + 2][k4 * 4];
        float4 x3 = *(const float4*)&Xs[ti * 4 + 3][k4 * 4];
        float4 w0 = Ws[(k4 * 4 + 0) * 16 + tj];
        float4 w1 = Ws[(k4 * 4 + 1) * 16 + tj];
        float4 w2 = Ws[(k4 * 4 + 2) * 16 + tj];
        float4 w3 = Ws[(k4 * 4 + 3) * 16 + tj];
#define FMA4(A, XV)                                                      \
        A.x += XV.x * w0.x + XV.y * w1.x + XV.z * w2.x + XV.w * w3.x;    \
        A.y += XV.x * w0.y + XV.y * w1.y + XV.z * w2.y + XV.w * w3.y;    \
        A.z += XV.x * w0.z + XV.y * w1.z + XV.z * w2.z + XV.w * w3.z;    \
        A.w += XV.x * w0.w + XV.y * w1.w + XV.z * w2.w + XV.w * w3.w;
        FMA4(a0, x0) FMA4(a1, x1) FMA4(a2, x2) FMA4(a3, x3)
#undef FMA4
    }
#pragma unroll
    for (int q = 0; q < 4; ++q) {
        int row = base + ti * 4 + q;
        if (row < n) {
            float d = dis[row];
            float4 a = (q == 0) ? a0 : (q == 1) ? a1 : (q == 2) ? a2 : a3;
            a.x *= d; a.y *= d; a.z *= d; a.w *= d;
            ((float4*)(Y + (size_t)row * 64))[tj] = a;
        }
    }
}

// ---- pull gather: out[i] = relu( dis[i]*(sum Hs[s] + Hs[i]) + b ) ----
__global__ __launch_bounds__(256) void k_gather(const float* __restrict__ Hs,
                                                const int* __restrict__ csr,
                                                const int* __restrict__ rowptr,
                                                const int* __restrict__ deg,
                                                const float* __restrict__ dis,
                                                const float* __restrict__ b,
                                                float* __restrict__ out, int n) {
    int node = blockIdx.x * 4 + (threadIdx.x >> 6);
    int lane = threadIdx.x & 63;
    if (node >= n) return;
    int base = rowptr[node];
    int cnt = deg[node];
    float dd = dis[node];
    float acc = 0.0f;
    int j = 0;
    for (; j + 8 <= cnt; j += 8) {
        int s0 = csr[base + j + 0], s1 = csr[base + j + 1];
        int s2 = csr[base + j + 2], s3 = csr[base + j + 3];
        int s4 = csr[base + j + 4], s5 = csr[base + j + 5];
        int s6 = csr[base + j + 6], s7 = csr[base + j + 7];
        acc += Hs[(size_t)s0 * 64 + lane] + Hs[(size_t)s1 * 64 + lane]
             + Hs[(size_t)s2 * 64 + lane] + Hs[(size_t)s3 * 64 + lane]
             + Hs[(size_t)s4 * 64 + lane] + Hs[(size_t)s5 * 64 + lane]
             + Hs[(size_t)s6 * 64 + lane] + Hs[(size_t)s7 * 64 + lane];
    }
    for (; j + 4 <= cnt; j += 4) {
        int s0 = csr[base + j + 0], s1 = csr[base + j + 1];
        int s2 = csr[base + j + 2], s3 = csr[base + j + 3];
        acc += Hs[(size_t)s0 * 64 + lane] + Hs[(size_t)s1 * 64 + lane]
             + Hs[(size_t)s2 * 64 + lane] + Hs[(size_t)s3 * 64 + lane];
    }
    for (; j < cnt; ++j)
        acc += Hs[(size_t)csr[base + j] * 64 + lane];
    float r = dd * (acc + Hs[(size_t)node * 64 + lane]) + b[lane];
    out[(size_t)node * 64 + lane] = fmaxf(r, 0.0f);
}

// ---- layer-2 gather with fused linear head ----
// s = relu( dis*(sum + self) + b2 ) * Wp[lane]; wave-reduce; out[node] = s + bp.
__global__ __launch_bounds__(256) void k_gather_head(const float* __restrict__ Hs,
                                                     const int* __restrict__ csr,
                                                     const int* __restrict__ rowptr,
                                                     const int* __restrict__ deg,
                                                     const float* __restrict__ dis,
                                                     const float* __restrict__ b,
                                                     const float* __restrict__ Wp,
                                                     const float* __restrict__ bp,
                                                     float* __restrict__ out, int n) {
    int node = blockIdx.x * 4 + (threadIdx.x >> 6);
    int lane = threadIdx.x & 63;
    if (node >= n) return;
    int base = rowptr[node];
    int cnt = deg[node];
    float dd = dis[node];
    float acc = 0.0f;
    int j = 0;
    for (; j + 8 <= cnt; j += 8) {
        int s0 = csr[base + j + 0], s1 = csr[base + j + 1];
        int s2 = csr[base + j + 2], s3 = csr[base + j + 3];
        int s4 = csr[base + j + 4], s5 = csr[base + j + 5];
        int s6 = csr[base + j + 6], s7 = csr[base + j + 7];
        acc += Hs[(size_t)s0 * 64 + lane] + Hs[(size_t)s1 * 64 + lane]
             + Hs[(size_t)s2 * 64 + lane] + Hs[(size_t)s3 * 64 + lane]
             + Hs[(size_t)s4 * 64 + lane] + Hs[(size_t)s5 * 64 + lane]
             + Hs[(size_t)s6 * 64 + lane] + Hs[(size_t)s7 * 64 + lane];
    }
    for (; j + 4 <= cnt; j += 4) {
        int s0 = csr[base + j + 0], s1 = csr[base + j + 1];
        int s2 = csr[base + j + 2], s3 = csr[base + j + 3];
        acc += Hs[(size_t)s0 * 64 + lane] + Hs[(size_t)s1 * 64 + lane]
             + Hs[(size_t)s2 * 64 + lane] + Hs[(size_t)s3 * 64 + lane];
    }
    for (; j < cnt; ++j)
        acc += Hs[(size_t)csr[base + j] * 64 + lane];
    float r = fmaxf(dd * (acc + Hs[(size_t)node * 64 + lane]) + b[lane], 0.0f);
    float s = r * Wp[lane];
#pragma unroll
    for (int m = 32; m >= 1; m >>= 1)
        s += __shfl_xor(s, m);
    if (lane == 0) out[node] = s + bp[0];
}

extern "C" void kernel_launch(void* const* d_in, const int* in_sizes, int n_in,
                              void* d_out, int out_size, void* d_ws, size_t ws_size,
                              hipStream_t stream) {
    const float* x  = (const float*)d_in[0];
    const int*   ei = (const int*)d_in[1];
    const float* W1 = (const float*)d_in[2];
    const float* b1 = (const float*)d_in[3];
    const float* W2 = (const float*)d_in[4];
    const float* b2 = (const float*)d_in[5];
    const float* Wp = (const float*)d_in[6];
    const float* bp = (const float*)d_in[7];
    float* out = (float*)d_out;

    const int N = GNN_N, E = GNN_E;
    const int* srcv = ei;
    const int* dstv = ei + E;

    // workspace layout (bytes):
    //   hist   @ 0         : NBLK*NBUCK ints
    //   bbase  @ 400,896   : 392 ints
    //   rowptr @ 402,944   : N ints
    //   deg    @ 802,944   : N ints
    //   dis    @ 1,202,944 : N floats
    //   csr    @ 1,603,584 : E ints
    //   bufA   @ 8,003,584 : N*64 floats
    //   bufB   @ 33,603,584: N*64 floats
    //   part   @ 33,603,584: E u32 -- aliases bufB (part dead before bufB written)
    char* ws = (char*)d_ws;
    int*   hist   = (int*)(ws + 0);
    int*   bbase  = (int*)(ws + 400896);
    int*   rowptr = (int*)(ws + 402944);
    int*   deg    = (int*)(ws + 802944);
    float* dis    = (float*)(ws + 1202944);
    int*   csr    = (int*)(ws + 1603584);
    float* bufA   = (float*)(ws + 8003584);
    float* bufB   = (float*)(ws + 33603584);
    unsigned int* part = (unsigned int*)(ws + 33603584);

    // CSR build
    k_hist   <<<NBLK, 256, 0, stream>>>(dstv, hist);
    k_colscan<<<1, 512, 0, stream>>>(hist, bbase);
    k_part   <<<NBLK, 256, 0, stream>>>(srcv, dstv, hist, bbase, part);
    k_bsort  <<<NBUCK, 256, 0, stream>>>(part, bbase, csr, rowptr, deg, dis);

    // layer 1
    k_mm64  <<<(N + 63) / 64, 256, 0, stream>>>(x, W1, dis, bufA, N);
    k_gather<<<(N + 3) / 4, 256, 0, stream>>>(bufA, csr, rowptr, deg, dis, b1, bufB, N);
    // layer 2 + head (fused)
    k_mm64  <<<(N + 63) / 64, 256, 0, stream>>>(bufB, W2, dis, bufA, N);
    k_gather_head<<<(N + 3) / 4, 256, 0, stream>>>(bufA, csr, rowptr, deg, dis, b2,
                                                   Wp, bp, out, N);
}